// Round 14
// baseline (17.974 us; speedup 1.0000x reference)
//
#include <hip/hip_runtime.h>

// Quanvolution, fused: every block recomputes the 162-coefficient observable
// tensor T from the weights in LDS, then contracts per-pixel.
//   z_q(f0..f3) = sum_{p in {I,Y,Z}^4} T_q[p] * prod_k v_k(p_k),
//   v_k = (1, -sin f_k, cos f_k)   (RX(f)|0> has <X>=0).
// T_q from 16 basis-state sims of the data-independent entangler U:
//   M_q[r,r'] = <r,0000|U^dag Z_q U|r',0000> (Hermitian -> 136 pairs)
//   -> Pauli transform -> T_q[81] (1/3 channel-mean folded in).
//
// Grid: 96 blocks x 1024 threads; setup replicated per block.
// Phase A (measured-best R11 config): qubits 0..3 local, q4..q7 = lane bits
// 0..3; 4 basis columns per wave, waves 0..3. DPP for xor1/xor2/xor8; xor4
// stays on the LDS pipe (DPP version measured slower).
// U stored COLUMN-major (cidx) so Phase-B Gram reads and Phase-A stores are
// contiguous ds_read_b128/ds_write_b128 (half the LDS instructions).

namespace {

// ---- VALU-pipe lane permutes ----
__device__ __forceinline__ float dpp_xor1(float x) {
    return __int_as_float(__builtin_amdgcn_mov_dpp(__float_as_int(x), 0xB1, 0xF, 0xF, true));
}
__device__ __forceinline__ float dpp_xor2(float x) {
    return __int_as_float(__builtin_amdgcn_mov_dpp(__float_as_int(x), 0x4E, 0xF, 0xF, true));
}
__device__ __forceinline__ float dpp_xor8(float x) {
    // row_ror:8 : within a 16-lane row, lane i reads lane (i+8)%16 == i^8
    return __int_as_float(__builtin_amdgcn_mov_dpp(__float_as_int(x), 0x128, 0xF, 0xF, true));
}

template<int M>
__device__ __forceinline__ void rx_local(float (&sr)[16], float (&si)[16], float c, float s) {
#pragma unroll
    for (int r = 0; r < 16; ++r) {
        if (r & M) continue;
        const int a = r, b = r | M;
        float nra = c*sr[a] + s*si[b], nia = c*si[a] - s*sr[b];
        float nrb = c*sr[b] + s*si[a], nib = c*si[b] - s*sr[a];
        sr[a]=nra; si[a]=nia; sr[b]=nrb; si[b]=nib;
    }
}

// RX on lane qubit via generic shuffle (mask 4 only)
__device__ __forceinline__ void rx_lane16(float (&sr)[16], float (&si)[16], float c, float s, int mask) {
#pragma unroll
    for (int r = 0; r < 16; ++r) {
        float orr = __shfl_xor(sr[r], mask, 64);
        float oii = __shfl_xor(si[r], mask, 64);
        sr[r] = c*sr[r] + s*oii;
        si[r] = c*si[r] - s*orr;
    }
}

// RX on lane qubit via DPP (masks 1,2,8)
template<int MASK>
__device__ __forceinline__ void rx_lane_dpp(float (&sr)[16], float (&si)[16], float c, float s) {
#pragma unroll
    for (int r = 0; r < 16; ++r) {
        float orr = (MASK == 1) ? dpp_xor1(sr[r]) : (MASK == 2) ? dpp_xor2(sr[r]) : dpp_xor8(sr[r]);
        float oii = (MASK == 1) ? dpp_xor1(si[r]) : (MASK == 2) ? dpp_xor2(si[r]) : dpp_xor8(si[r]);
        sr[r] = c*sr[r] + s*oii;
        si[r] = c*si[r] - s*orr;
    }
}

template<int C, int T>
__device__ __forceinline__ void cnot_ll(float (&sr)[16], float (&si)[16]) {
#pragma unroll
    for (int r = 0; r < 16; ++r) {
        if (!(r & C) || (r & T)) continue;
        const int a = r, b = r ^ T;
        float tr=sr[a], ti=si[a];
        sr[a]=sr[b]; si[a]=si[b];
        sr[b]=tr;    si[b]=ti;
    }
}

__device__ __forceinline__ void entangler(float (&sr)[16], float (&si)[16],
                                          const float* __restrict__ w, int lane) {
    float c, s;
#pragma unroll 1   // keep code size down (icache); loop body is large
    for (int l = 0; l < 2; ++l) {
        __sincosf(0.5f*w[l*8+0], &s, &c); rx_local<1>(sr, si, c, s);
        __sincosf(0.5f*w[l*8+1], &s, &c); rx_local<2>(sr, si, c, s);
        __sincosf(0.5f*w[l*8+2], &s, &c); rx_local<4>(sr, si, c, s);
        __sincosf(0.5f*w[l*8+3], &s, &c); rx_local<8>(sr, si, c, s);
        __sincosf(0.5f*w[l*8+4], &s, &c); rx_lane_dpp<1>(sr, si, c, s);   // q4: DPP
        __sincosf(0.5f*w[l*8+5], &s, &c); rx_lane_dpp<2>(sr, si, c, s);   // q5: DPP
        __sincosf(0.5f*w[l*8+6], &s, &c); rx_lane16(sr, si, c, s, 4);     // q6: LDS
        __sincosf(0.5f*w[l*8+7], &s, &c); rx_lane_dpp<8>(sr, si, c, s);   // q7: DPP

        cnot_ll<1,2>(sr, si);   // (0,1)
        cnot_ll<2,4>(sr, si);   // (1,2)
        cnot_ll<4,8>(sr, si);   // (2,3)
#pragma unroll
        for (int r = 8; r < 16; ++r) {           // (3,4): xor1 -> DPP
            sr[r] = dpp_xor1(sr[r]);
            si[r] = dpp_xor1(si[r]);
        }
        {                                         // (4,5): ctrl lane b0, xor2 -> DPP
            const bool ctrl = lane & 1;
#pragma unroll
            for (int r = 0; r < 16; ++r) {
                float orr = dpp_xor2(sr[r]);
                float oii = dpp_xor2(si[r]);
                sr[r] = ctrl ? orr : sr[r];
                si[r] = ctrl ? oii : si[r];
            }
        }
        {                                         // (5,6): ctrl lane b1, xor4 -> LDS
            const bool ctrl = (lane >> 1) & 1;
#pragma unroll
            for (int r = 0; r < 16; ++r) {
                float orr = __shfl_xor(sr[r], 4, 64);
                float oii = __shfl_xor(si[r], 4, 64);
                sr[r] = ctrl ? orr : sr[r];
                si[r] = ctrl ? oii : si[r];
            }
        }
        {                                         // (6,7): ctrl lane b2, xor8 -> DPP
            const bool ctrl = (lane >> 2) & 1;
#pragma unroll
            for (int r = 0; r < 16; ++r) {
                float orr = dpp_xor8(sr[r]);
                float oii = dpp_xor8(si[r]);
                sr[r] = ctrl ? orr : sr[r];
                si[r] = ctrl ? oii : si[r];
            }
        }
        {                                         // (7,0): ctrl lane b3, local pair swap
            const bool c7 = (lane >> 3) & 1;
#pragma unroll
            for (int r = 0; r < 16; r += 2) {
                float ar = c7 ? sr[r+1] : sr[r];
                float ai = c7 ? si[r+1] : si[r];
                float br = c7 ? sr[r]   : sr[r+1];
                float bi = c7 ? si[r]   : si[r+1];
                sr[r]=ar; si[r]=ai; sr[r+1]=br; si[r+1]=bi;
            }
        }
    }
}

// column-major U: column g, element n. +2 float2 pad per 16 n's keeps
// 16B alignment for b128 and staggers banks. CSTRIDE = 256 + 16*2 + 2.
#define CSTRIDE 290
__device__ __forceinline__ int cidx(int g, int n) { return g*CSTRIDE + n + ((n>>4)<<1); }

__device__ __forceinline__ void tri_decode(int t, int& rr, int& rp) {
    int r = 0, rem = t;
    while (rem >= 16 - r) { rem -= 16 - r; ++r; }
    rr = r; rp = r + rem;
}

__device__ __forceinline__ int ilv(int bra, int ket) {
    int idx = 0;
#pragma unroll
    for (int k = 0; k < 4; ++k)
        idx |= (((bra>>k)&1) << (2*k+1)) | (((ket>>k)&1) << (2*k));
    return idx;
}

// embedding vectors from the 12 loaded patch values
__device__ __forceinline__ void emb_sincos(const float (&f)[12],
                                           float (&vy)[3][4], float (&vz)[3][4]) {
#pragma unroll
    for (int c = 0; c < 3; ++c) {
#pragma unroll
        for (int k = 0; k < 4; ++k) {
            float s, co;
            __sincosf(f[c*4+k], &s, &co);
            vy[c][k] = -s; vz[c][k] = co;
        }
    }
}

} // namespace

#define NPIX (8*39*39)   // 12168
#define BLK  1024
#define PPB  128
#define NBLK ((NPIX + PPB - 1) / PPB)   // 96

__global__ __launch_bounds__(1024) void quanv_fused(
    const float* __restrict__ x,   // (8,3,40,40)
    const float* __restrict__ w,   // (2,8)
    float* __restrict__ out)       // (8,2,39,39)
{
    __shared__ __align__(16) float2 U[16*CSTRIDE];   // column-major, padded
    __shared__ float2 XA[2][256];
    __shared__ float2 XB[2][256];
    __shared__ float2 PB[4][2][136];     // [quarter][q][pair] Gram partials
    __shared__ __align__(16) float Tp[216];  // [q][27][4] = (t0,t1,t2,pad)

    const int tid  = (int)threadIdx.x;
    const int lane = tid & 63;

    // ---- contraction threads: waves 4-7 (tid 256..511), 128 pixels x 2 q ----
    const int gp   = tid - 256;
    const int gpix = (int)blockIdx.x * PPB + (gp & 127);
    const int half = (gp >> 7) & 1;
    const bool is_contract = (tid >= 256) && (tid < 512) && (gpix < NPIX);

    const int pid = (gpix < NPIX) ? gpix : (NPIX - 1);
    const int j  = pid % 39;
    const int t2 = pid / 39;
    const int i  = t2 % 39;
    const int b  = t2 / 39;

    float f[12];
    float vy[3][4], vz[3][4];
    if (tid >= 256 && tid < 512) {
        // issue pixel loads early; latency hides under Phase A
#pragma unroll
        for (int c = 0; c < 3; ++c) {
            const float* xp = x + (((b*3 + c)*40) + i)*40 + j;
            f[c*4+0] = xp[0];  f[c*4+1] = xp[1];
            f[c*4+2] = xp[40]; f[c*4+3] = xp[41];
        }
    }

    // ---- Phase A: 16 basis-state sims on waves 0-3; waves 4-7 do their
    // ---- embedding sincos in the idle slot ----
    if (tid < 256) {
        const int g = (tid >> 6) * 4 + (lane >> 4);
        float sr[16], si[16];
#pragma unroll
        for (int r = 0; r < 16; ++r) {
            sr[r] = (((lane & 15) == 0) && (r == g)) ? 1.f : 0.f;
            si[r] = 0.f;
        }
        entangler(sr, si, w, lane);
        // lane owns n = (lane&15)*16 + r, r=0..15 -> contiguous in column g
        const int base = cidx(g, (lane & 15) << 4);
#pragma unroll
        for (int r = 0; r < 16; r += 2) {
            *reinterpret_cast<float4*>(&U[base + r]) =
                make_float4(sr[r], si[r], sr[r+1], si[r+1]);
        }
    } else if (tid < 512) {
        emb_sincos(f, vy, vz);
    }
    __syncthreads();

    // ---- Phase B: Hermitian Gram partials, 136 pairs x 4-way n-split,
    // ---- vectorized ds_read_b128 column walks ----
    if (tid < 544) {
        const int t = tid >> 2, quarter = tid & 3;
        int rr, rp; tri_decode(t, rr, rp);
        float2 a0={0,0}, a1={0,0}, a2={0,0}, a3={0,0};
        const int n0 = quarter * 64;
#pragma unroll
        for (int sub = 0; sub < 4; ++sub) {
            const float4* cr = reinterpret_cast<const float4*>(&U[cidx(rr, n0 + sub*16)]);
            const float4* cp = reinterpret_cast<const float4*>(&U[cidx(rp, n0 + sub*16)]);
#pragma unroll
            for (int ii = 0; ii < 8; ++ii) {
                const float4 ua = cr[ii];   // n = n0+sub*16+2*ii : (re,im,re,im)
                const float4 ub = cp[ii];
                const float cre0 = ua.x*ub.x + ua.y*ub.y;
                const float cim0 = ua.x*ub.y - ua.y*ub.x;
                const float cre1 = ua.z*ub.z + ua.w*ub.w;
                const float cim1 = ua.z*ub.w - ua.w*ub.z;
                if ((ii & 1) == 0) {        // n%4 = 0,1 -> cls 0,1
                    a0.x += cre0; a0.y += cim0;
                    a1.x += cre1; a1.y += cim1;
                } else {                    // n%4 = 2,3 -> cls 2,3
                    a2.x += cre0; a2.y += cim0;
                    a3.x += cre1; a3.y += cim1;
                }
            }
        }
        PB[quarter][0][t] = make_float2((a0.x - a1.x) + (a2.x - a3.x),
                                        (a0.y - a1.y) + (a2.y - a3.y));
        PB[quarter][1][t] = make_float2((a0.x + a1.x) - (a2.x + a3.x),
                                        (a0.y + a1.y) - (a2.y + a3.y));
    }
    __syncthreads();

    // ---- combine quarters + Hermitian mirror + bit-interleave ----
    if (tid < 136) {
        int rr, rp; tri_decode(tid, rr, rp);
        const int idx  = ilv(rr, rp);
        const int idxT = ilv(rp, rr);
#pragma unroll
        for (int q = 0; q < 2; ++q) {
            float2 m = PB[0][q][tid];
            m.x += PB[1][q][tid].x + PB[2][q][tid].x + PB[3][q][tid].x;
            m.y += PB[1][q][tid].y + PB[2][q][tid].y + PB[3][q][tid].y;
            XA[q][idxT] = make_float2(m.x, -m.y);
            XA[q][idx]  = m;
        }
    }
    __syncthreads();

    // ---- Phase C: Pauli transform along 4 qubit axes ----
    float2 (*A)[256] = XA;
    float2 (*B)[256] = XB;
    for (int k = 0; k < 4; ++k) {
        if (tid < 128) {
            const int q = tid >> 6, quad = tid & 63;
            const int st = 1 << (2*k);
            const int ml = st - 1;
            const int base = (quad & ml) | ((quad & ~ml) << 2);
            const float2 i00 = A[q][base],      i01 = A[q][base+st];
            const float2 i10 = A[q][base+2*st], i11 = A[q][base+3*st];
            B[q][base]      = make_float2(0.5f*(i00.x+i11.x), 0.5f*(i00.y+i11.y)); // I
            B[q][base+st]   = make_float2(0.5f*(i01.x+i10.x), 0.5f*(i01.y+i10.y)); // X
            B[q][base+2*st] = make_float2(-0.5f*(i01.y-i10.y), 0.5f*(i01.x-i10.x)); // Y
            B[q][base+3*st] = make_float2(0.5f*(i00.x-i11.x), 0.5f*(i00.y-i11.y)); // Z
        }
        __syncthreads();
        float2 (*t)[256] = A; A = B; B = t;
    }

    // ---- Phase D: extract {I,Y,Z}^4 real coefficients (1/3 folded) ----
    if (tid < 162) {
        const int q = tid / 81, u = tid % 81;
        const int i0 = u % 3, i1 = (u/3) % 3, i2 = (u/9) % 3, i3 = u / 27;
        const int p0 = (i0==0)?0:(i0+1);
        const int p1 = (i1==0)?0:(i1+1);
        const int p2 = (i2==0)?0:(i2+1);
        const int p3 = (i3==0)?0:(i3+1);
        const int idx = p0 | (p1<<2) | (p2<<4) | (p3<<6);
        Tp[q*108 + (u/3)*4 + i0] = A[q][idx].x * (1.f/3.f);
    }
    __syncthreads();

    // ---- contraction: one (pixel, q) per thread, waves 4-7 ----
    if (is_contract) {
        float a3[3] = {0.f, 0.f, 0.f};
#pragma unroll
        for (int i3 = 0; i3 < 3; ++i3) {
            float a2[3] = {0.f, 0.f, 0.f};
#pragma unroll
            for (int i2 = 0; i2 < 3; ++i2) {
                float a1[3] = {0.f, 0.f, 0.f};
#pragma unroll
                for (int i1 = 0; i1 < 3; ++i1) {
                    const float4 tv = *reinterpret_cast<const float4*>(
                        &Tp[half*108 + ((i3*3 + i2)*3 + i1)*4]);
#pragma unroll
                    for (int c = 0; c < 3; ++c) {
                        const float s = fmaf(tv.z, vz[c][0], fmaf(tv.y, vy[c][0], tv.x));
                        if      (i1 == 0) a1[c] += s;
                        else if (i1 == 1) a1[c] = fmaf(s, vy[c][1], a1[c]);
                        else              a1[c] = fmaf(s, vz[c][1], a1[c]);
                    }
                }
#pragma unroll
                for (int c = 0; c < 3; ++c) {
                    if      (i2 == 0) a2[c] += a1[c];
                    else if (i2 == 1) a2[c] = fmaf(a1[c], vy[c][2], a2[c]);
                    else              a2[c] = fmaf(a1[c], vz[c][2], a2[c]);
                }
            }
#pragma unroll
            for (int c = 0; c < 3; ++c) {
                if      (i3 == 0) a3[c] += a2[c];
                else if (i3 == 1) a3[c] = fmaf(a2[c], vy[c][3], a3[c]);
                else              a3[c] = fmaf(a2[c], vz[c][3], a3[c]);
            }
        }

        out[((b*2 + half)*39 + i)*39 + j] = a3[0] + a3[1] + a3[2];
    }
}

extern "C" void kernel_launch(void* const* d_in, const int* in_sizes, int n_in,
                              void* d_out, int out_size, void* d_ws, size_t ws_size,
                              hipStream_t stream) {
    const float* x = (const float*)d_in[0];
    const float* w = (const float*)d_in[1];
    float* out = (float*)d_out;

    quanv_fused<<<NBLK, BLK, 0, stream>>>(x, w, out);
}

// Round 15
// 16.812 us; speedup vs baseline: 1.0692x; 1.0692x over previous
//
#include <hip/hip_runtime.h>

// Quanvolution, fused: every block recomputes the 162-coefficient observable
// tensor T from the weights in LDS, then contracts per-pixel.
//   z_q(f0..f3) = sum_{p in {I,Y,Z}^4} T_q[p] * prod_k v_k(p_k),
//   v_k = (1, -sin f_k, cos f_k)   (RX(f)|0> has <X>=0).
// T_q from 16 basis-state sims of the data-independent entangler U:
//   M_q[r,r'] = <r,0000|U^dag Z_q U|r',0000> (Hermitian -> 136 pairs)
//   -> Pauli transform -> T_q[81] (1/3 channel-mean folded in).
//
// Grid: 96 blocks x 576 threads (9 waves; max concurrent need is 544).
// Phase A (measured-best R11): qubits 0..3 local, q4..q7 = lane bits 0..3;
// DPP for xor1/xor2/xor8; xor4 stays on the LDS pipe (DPP version slower).
// Phase C: two fused 2-axis passes (bit-identical math, half the barriers).

namespace {

// ---- VALU-pipe lane permutes ----
__device__ __forceinline__ float dpp_xor1(float x) {
    return __int_as_float(__builtin_amdgcn_mov_dpp(__float_as_int(x), 0xB1, 0xF, 0xF, true));
}
__device__ __forceinline__ float dpp_xor2(float x) {
    return __int_as_float(__builtin_amdgcn_mov_dpp(__float_as_int(x), 0x4E, 0xF, 0xF, true));
}
__device__ __forceinline__ float dpp_xor8(float x) {
    // row_ror:8 : within a 16-lane row, lane i reads lane (i+8)%16 == i^8
    return __int_as_float(__builtin_amdgcn_mov_dpp(__float_as_int(x), 0x128, 0xF, 0xF, true));
}

template<int M>
__device__ __forceinline__ void rx_local(float (&sr)[16], float (&si)[16], float c, float s) {
#pragma unroll
    for (int r = 0; r < 16; ++r) {
        if (r & M) continue;
        const int a = r, b = r | M;
        float nra = c*sr[a] + s*si[b], nia = c*si[a] - s*sr[b];
        float nrb = c*sr[b] + s*si[a], nib = c*si[b] - s*sr[a];
        sr[a]=nra; si[a]=nia; sr[b]=nrb; si[b]=nib;
    }
}

// RX on lane qubit via generic shuffle (mask 4 only)
__device__ __forceinline__ void rx_lane16(float (&sr)[16], float (&si)[16], float c, float s, int mask) {
#pragma unroll
    for (int r = 0; r < 16; ++r) {
        float orr = __shfl_xor(sr[r], mask, 64);
        float oii = __shfl_xor(si[r], mask, 64);
        sr[r] = c*sr[r] + s*oii;
        si[r] = c*si[r] - s*orr;
    }
}

// RX on lane qubit via DPP (masks 1,2,8)
template<int MASK>
__device__ __forceinline__ void rx_lane_dpp(float (&sr)[16], float (&si)[16], float c, float s) {
#pragma unroll
    for (int r = 0; r < 16; ++r) {
        float orr = (MASK == 1) ? dpp_xor1(sr[r]) : (MASK == 2) ? dpp_xor2(sr[r]) : dpp_xor8(sr[r]);
        float oii = (MASK == 1) ? dpp_xor1(si[r]) : (MASK == 2) ? dpp_xor2(si[r]) : dpp_xor8(si[r]);
        sr[r] = c*sr[r] + s*oii;
        si[r] = c*si[r] - s*orr;
    }
}

template<int C, int T>
__device__ __forceinline__ void cnot_ll(float (&sr)[16], float (&si)[16]) {
#pragma unroll
    for (int r = 0; r < 16; ++r) {
        if (!(r & C) || (r & T)) continue;
        const int a = r, b = r ^ T;
        float tr=sr[a], ti=si[a];
        sr[a]=sr[b]; si[a]=si[b];
        sr[b]=tr;    si[b]=ti;
    }
}

__device__ __forceinline__ void entangler(float (&sr)[16], float (&si)[16],
                                          const float* __restrict__ w, int lane) {
    float c, s;
#pragma unroll 1   // keep code size down (icache); loop body is large
    for (int l = 0; l < 2; ++l) {
        __sincosf(0.5f*w[l*8+0], &s, &c); rx_local<1>(sr, si, c, s);
        __sincosf(0.5f*w[l*8+1], &s, &c); rx_local<2>(sr, si, c, s);
        __sincosf(0.5f*w[l*8+2], &s, &c); rx_local<4>(sr, si, c, s);
        __sincosf(0.5f*w[l*8+3], &s, &c); rx_local<8>(sr, si, c, s);
        __sincosf(0.5f*w[l*8+4], &s, &c); rx_lane_dpp<1>(sr, si, c, s);   // q4: DPP
        __sincosf(0.5f*w[l*8+5], &s, &c); rx_lane_dpp<2>(sr, si, c, s);   // q5: DPP
        __sincosf(0.5f*w[l*8+6], &s, &c); rx_lane16(sr, si, c, s, 4);     // q6: LDS
        __sincosf(0.5f*w[l*8+7], &s, &c); rx_lane_dpp<8>(sr, si, c, s);   // q7: DPP

        cnot_ll<1,2>(sr, si);   // (0,1)
        cnot_ll<2,4>(sr, si);   // (1,2)
        cnot_ll<4,8>(sr, si);   // (2,3)
#pragma unroll
        for (int r = 8; r < 16; ++r) {           // (3,4): xor1 -> DPP
            sr[r] = dpp_xor1(sr[r]);
            si[r] = dpp_xor1(si[r]);
        }
        {                                         // (4,5): ctrl lane b0, xor2 -> DPP
            const bool ctrl = lane & 1;
#pragma unroll
            for (int r = 0; r < 16; ++r) {
                float orr = dpp_xor2(sr[r]);
                float oii = dpp_xor2(si[r]);
                sr[r] = ctrl ? orr : sr[r];
                si[r] = ctrl ? oii : si[r];
            }
        }
        {                                         // (5,6): ctrl lane b1, xor4 -> LDS
            const bool ctrl = (lane >> 1) & 1;
#pragma unroll
            for (int r = 0; r < 16; ++r) {
                float orr = __shfl_xor(sr[r], 4, 64);
                float oii = __shfl_xor(si[r], 4, 64);
                sr[r] = ctrl ? orr : sr[r];
                si[r] = ctrl ? oii : si[r];
            }
        }
        {                                         // (6,7): ctrl lane b2, xor8 -> DPP
            const bool ctrl = (lane >> 2) & 1;
#pragma unroll
            for (int r = 0; r < 16; ++r) {
                float orr = dpp_xor8(sr[r]);
                float oii = dpp_xor8(si[r]);
                sr[r] = ctrl ? orr : sr[r];
                si[r] = ctrl ? oii : si[r];
            }
        }
        {                                         // (7,0): ctrl lane b3, local pair swap
            const bool c7 = (lane >> 3) & 1;
#pragma unroll
            for (int r = 0; r < 16; r += 2) {
                float ar = c7 ? sr[r+1] : sr[r];
                float ai = c7 ? si[r+1] : si[r];
                float br = c7 ? sr[r]   : sr[r+1];
                float bi = c7 ? si[r]   : si[r+1];
                sr[r]=ar; si[r]=ai; sr[r+1]=br; si[r+1]=bi;
            }
        }
    }
}

__device__ __forceinline__ int uidx(int n, int g) { return n*16 + g + (n>>4); }

__device__ __forceinline__ void tri_decode(int t, int& rr, int& rp) {
    int r = 0, rem = t;
    while (rem >= 16 - r) { rem -= 16 - r; ++r; }
    rr = r; rp = r + rem;
}

__device__ __forceinline__ int ilv(int bra, int ket) {
    int idx = 0;
#pragma unroll
    for (int k = 0; k < 4; ++k)
        idx |= (((bra>>k)&1) << (2*k+1)) | (((ket>>k)&1) << (2*k));
    return idx;
}

// 4-point Pauli transform, identical FP ops to the original per-axis step
__device__ __forceinline__ void pauli4(const float2 i00, const float2 i01,
                                       const float2 i10, const float2 i11,
                                       float2& oI, float2& oX, float2& oY, float2& oZ) {
    oI = make_float2(0.5f*(i00.x+i11.x), 0.5f*(i00.y+i11.y));
    oX = make_float2(0.5f*(i01.x+i10.x), 0.5f*(i01.y+i10.y));
    oY = make_float2(-0.5f*(i01.y-i10.y), 0.5f*(i01.x-i10.x));
    oZ = make_float2(0.5f*(i00.x-i11.x), 0.5f*(i00.y-i11.y));
}

// fused 2-axis pass: strides st1 (axis applied first) and st2, on one
// 16-element group at `base`. Reads src, writes dst.
__device__ __forceinline__ void pauli_pass2(const float2* src, float2* dst,
                                            int base, int st1, int st2) {
    float2 v[4][4];   // [a][b] = src[base + a*st1 + b*st2]
#pragma unroll
    for (int a = 0; a < 4; ++a)
#pragma unroll
        for (int bq = 0; bq < 4; ++bq)
            v[a][bq] = src[base + a*st1 + bq*st2];
    float2 t[4][4];   // axis-1 transform (over a), per b
#pragma unroll
    for (int bq = 0; bq < 4; ++bq)
        pauli4(v[0][bq], v[1][bq], v[2][bq], v[3][bq],
               t[0][bq], t[1][bq], t[2][bq], t[3][bq]);
    float2 o[4][4];   // axis-2 transform (over b), per p1
#pragma unroll
    for (int p1 = 0; p1 < 4; ++p1)
        pauli4(t[p1][0], t[p1][1], t[p1][2], t[p1][3],
               o[p1][0], o[p1][1], o[p1][2], o[p1][3]);
#pragma unroll
    for (int p1 = 0; p1 < 4; ++p1)
#pragma unroll
        for (int p2 = 0; p2 < 4; ++p2)
            dst[base + p1*st1 + p2*st2] = o[p1][p2];
}

// embedding vectors from the 12 loaded patch values
__device__ __forceinline__ void emb_sincos(const float (&f)[12],
                                           float (&vy)[3][4], float (&vz)[3][4]) {
#pragma unroll
    for (int c = 0; c < 3; ++c) {
#pragma unroll
        for (int k = 0; k < 4; ++k) {
            float s, co;
            __sincosf(f[c*4+k], &s, &co);
            vy[c][k] = -s; vz[c][k] = co;
        }
    }
}

} // namespace

#define NPIX (8*39*39)   // 12168
#define BLK  576
#define PPB  128
#define NBLK ((NPIX + PPB - 1) / PPB)   // 96

__global__ __launch_bounds__(576) void quanv_fused(
    const float* __restrict__ x,   // (8,3,40,40)
    const float* __restrict__ w,   // (2,8)
    float* __restrict__ out)       // (8,2,39,39)
{
    __shared__ float2 U[16*256 + 16];    // U[n][g], padded
    __shared__ float2 XA[2][256];
    __shared__ float2 XB[2][256];
    __shared__ float2 PB[4][2][136];     // [quarter][q][pair] Gram partials
    __shared__ __align__(16) float Tp[216];  // [q][27][4] = (t0,t1,t2,pad)

    const int tid  = (int)threadIdx.x;
    const int lane = tid & 63;

    // ---- contraction threads: waves 4-7 (tid 256..511), 128 pixels x 2 q ----
    const int gp   = tid - 256;
    const int gpix = (int)blockIdx.x * PPB + (gp & 127);
    const int half = (gp >> 7) & 1;
    const bool is_contract = (tid >= 256) && (tid < 512) && (gpix < NPIX);

    const int pid = (gpix < NPIX) ? gpix : (NPIX - 1);
    const int j  = pid % 39;
    const int t2 = pid / 39;
    const int i  = t2 % 39;
    const int b  = t2 / 39;

    float f[12];
    float vy[3][4], vz[3][4];
    if (tid >= 256 && tid < 512) {
        // issue pixel loads early; latency hides under Phase A
#pragma unroll
        for (int c = 0; c < 3; ++c) {
            const float* xp = x + (((b*3 + c)*40) + i)*40 + j;
            f[c*4+0] = xp[0];  f[c*4+1] = xp[1];
            f[c*4+2] = xp[40]; f[c*4+3] = xp[41];
        }
    }

    // ---- Phase A: 16 basis-state sims on waves 0-3; waves 4-7 do their
    // ---- embedding sincos in the idle slot ----
    if (tid < 256) {
        const int g = (tid >> 6) * 4 + (lane >> 4);
        float sr[16], si[16];
#pragma unroll
        for (int r = 0; r < 16; ++r) {
            sr[r] = (((lane & 15) == 0) && (r == g)) ? 1.f : 0.f;
            si[r] = 0.f;
        }
        entangler(sr, si, w, lane);
#pragma unroll
        for (int r = 0; r < 16; ++r) {
            const int n = ((lane & 15) << 4) | r;
            U[uidx(n, g)] = make_float2(sr[r], si[r]);
        }
    } else if (tid < 512) {
        emb_sincos(f, vy, vz);
    }
    __syncthreads();

    // ---- Phase B: Hermitian Gram partials, 136 pairs x 4-way n-split ----
    if (tid < 544) {
        const int t = tid >> 2, quarter = tid & 3;
        int rr, rp; tri_decode(t, rr, rp);
        float2 a0={0,0}, a1={0,0}, a2={0,0}, a3={0,0};
        const int n0 = quarter * 64;
        for (int n = n0; n < n0 + 64; n += 4) {
#pragma unroll
            for (int cls = 0; cls < 4; ++cls) {
                const float2 ur = U[uidx(n+cls, rr)];
                const float2 up = U[uidx(n+cls, rp)];
                const float cre = ur.x*up.x + ur.y*up.y;
                const float cim = ur.x*up.y - ur.y*up.x;
                if      (cls==0) { a0.x += cre; a0.y += cim; }
                else if (cls==1) { a1.x += cre; a1.y += cim; }
                else if (cls==2) { a2.x += cre; a2.y += cim; }
                else             { a3.x += cre; a3.y += cim; }
            }
        }
        PB[quarter][0][t] = make_float2((a0.x - a1.x) + (a2.x - a3.x),
                                        (a0.y - a1.y) + (a2.y - a3.y));
        PB[quarter][1][t] = make_float2((a0.x + a1.x) - (a2.x + a3.x),
                                        (a0.y + a1.y) - (a2.y + a3.y));
    }
    __syncthreads();

    // ---- combine quarters + Hermitian mirror + bit-interleave ----
    if (tid < 136) {
        int rr, rp; tri_decode(tid, rr, rp);
        const int idx  = ilv(rr, rp);
        const int idxT = ilv(rp, rr);
#pragma unroll
        for (int q = 0; q < 2; ++q) {
            float2 m = PB[0][q][tid];
            m.x += PB[1][q][tid].x + PB[2][q][tid].x + PB[3][q][tid].x;
            m.y += PB[1][q][tid].y + PB[2][q][tid].y + PB[3][q][tid].y;
            XA[q][idxT] = make_float2(m.x, -m.y);
            XA[q][idx]  = m;
        }
    }
    __syncthreads();

    // ---- Phase C: Pauli transform, 2 fused 2-axis passes (was 4 passes) ----
    // pass 1: axes 0 (st=1) then 1 (st=4); group = bits 4-7
    if (tid < 32) {
        const int q = tid >> 4, pos = tid & 15;
        pauli_pass2(XA[q], XB[q], pos << 4, 1, 4);
    }
    __syncthreads();
    // pass 2: axes 2 (st=16) then 3 (st=64); group = bits 0-3
    if (tid < 32) {
        const int q = tid >> 4, pos = tid & 15;
        pauli_pass2(XB[q], XA[q], pos, 16, 64);
    }
    __syncthreads();

    // ---- Phase D: extract {I,Y,Z}^4 real coefficients (1/3 folded) ----
    if (tid < 162) {
        const int q = tid / 81, u = tid % 81;
        const int i0 = u % 3, i1 = (u/3) % 3, i2 = (u/9) % 3, i3 = u / 27;
        const int p0 = (i0==0)?0:(i0+1);
        const int p1 = (i1==0)?0:(i1+1);
        const int p2 = (i2==0)?0:(i2+1);
        const int p3 = (i3==0)?0:(i3+1);
        const int idx = p0 | (p1<<2) | (p2<<4) | (p3<<6);
        Tp[q*108 + (u/3)*4 + i0] = XA[q][idx].x * (1.f/3.f);
    }
    __syncthreads();

    // ---- contraction: one (pixel, q) per thread, waves 4-7 ----
    if (is_contract) {
        float a3[3] = {0.f, 0.f, 0.f};
#pragma unroll
        for (int i3 = 0; i3 < 3; ++i3) {
            float a2[3] = {0.f, 0.f, 0.f};
#pragma unroll
            for (int i2 = 0; i2 < 3; ++i2) {
                float a1[3] = {0.f, 0.f, 0.f};
#pragma unroll
                for (int i1 = 0; i1 < 3; ++i1) {
                    const float4 tv = *reinterpret_cast<const float4*>(
                        &Tp[half*108 + ((i3*3 + i2)*3 + i1)*4]);
#pragma unroll
                    for (int c = 0; c < 3; ++c) {
                        const float s = fmaf(tv.z, vz[c][0], fmaf(tv.y, vy[c][0], tv.x));
                        if      (i1 == 0) a1[c] += s;
                        else if (i1 == 1) a1[c] = fmaf(s, vy[c][1], a1[c]);
                        else              a1[c] = fmaf(s, vz[c][1], a1[c]);
                    }
                }
#pragma unroll
                for (int c = 0; c < 3; ++c) {
                    if      (i2 == 0) a2[c] += a1[c];
                    else if (i2 == 1) a2[c] = fmaf(a1[c], vy[c][2], a2[c]);
                    else              a2[c] = fmaf(a1[c], vz[c][2], a2[c]);
                }
            }
#pragma unroll
            for (int c = 0; c < 3; ++c) {
                if      (i3 == 0) a3[c] += a2[c];
                else if (i3 == 1) a3[c] = fmaf(a2[c], vy[c][3], a3[c]);
                else              a3[c] = fmaf(a2[c], vz[c][3], a3[c]);
            }
        }

        out[((b*2 + half)*39 + i)*39 + j] = a3[0] + a3[1] + a3[2];
    }
}

extern "C" void kernel_launch(void* const* d_in, const int* in_sizes, int n_in,
                              void* d_out, int out_size, void* d_ws, size_t ws_size,
                              hipStream_t stream) {
    const float* x = (const float*)d_in[0];
    const float* w = (const float*)d_in[1];
    float* out = (float*)d_out;

    quanv_fused<<<NBLK, BLK, 0, stream>>>(x, w, out);
}